// Round 1
// baseline (971.449 us; speedup 1.0000x reference)
//
#include <hip/hip_runtime.h>

// SimpleRNN: T=64 steps, B=8, H=512, I=256, O=8, G=4, GS=64
// E_H = int(0.8*512) = 409 ; ZC = round(0.2*512) = 102 ; exist: j<410
#define T_N 64
#define B_N 8
#define H_N 512
#define I_N 256
#define O_N 8
#define G_N 4

constexpr float DT_ = 0.02f;
constexpr float AX_ = 0.2f;   // DT/0.1
constexpr float AW_ = 0.02f;  // DT/1.0

__device__ __forceinline__ float wave_sum(float v) {
#pragma unroll
    for (int off = 32; off >= 1; off >>= 1)
        v += __shfl_xor(v, off, 64);
    return v;  // all 64 lanes hold the identical full sum
}

// One wave per (b,h). 256 blocks x 1024 threads = 4096 waves.
// Block bk: b = bk>>5 (32 blocks per batch), h = (bk&31)*16 + waveId.
// Plastic state wx[b,h,:], wh[b,h,:] lives in registers for all 64 steps.
// Inter-step sync: per-batch 32-block barrier (monotonic counter in d_ws).
__global__ __launch_bounds__(1024, 4) void rnn_scan(
    const float* __restrict__ x, const float* __restrict__ Rs,
    const float* __restrict__ W_x2h, const float* __restrict__ W_h2h,
    const float* __restrict__ b_h2h, const float* __restrict__ W_h2o,
    const float* __restrict__ W_attn, const float* __restrict__ b_attn,
    const float* __restrict__ kappa, float* __restrict__ d_out,
    unsigned* __restrict__ barrier_cnt)
{
    float* os = d_out;                      // [T][B][O]
    float* hs = d_out + T_N * B_N * O_N;    // [T][B][H]

    const int tid  = threadIdx.x;
    const int wid  = tid >> 6;
    const int lane = tid & 63;
    const int bk   = blockIdx.x;            // 0..255
    const int b    = bk >> 5;               // 0..7
    const int h    = ((bk & 31) << 4) | wid; // 0..511

    // eff_attn = relu(W_attn) * sign * exist, cached in LDS (G*H = 8 KB)
    __shared__ float s_ea[G_N * H_N];
    for (int idx = tid; idx < G_N * H_N; idx += 1024) {
        int j = idx & (H_N - 1);
        float w = W_attn[idx];
        w = w > 0.0f ? w : 0.0f;
        float m = (j < 409) ? 1.0f : -1.0f;
        if (j >= 410) m = 0.0f;
        s_ea[idx] = w * m;
    }

    // persistent per-lane state: lane covers i = lane+64c (c<4), j = lane+64c (c<8)
    float Wxp[4], wx[4];
#pragma unroll
    for (int c = 0; c < 4; ++c) {
        float w = W_x2h[h * I_N + lane + 64 * c];
        Wxp[c] = w > 0.0f ? w : 0.0f;   // relu'd weight == clamp floor
        wx[c]  = 0.0f;
    }
    float Whp[8], wh[8], msk[8];
#pragma unroll
    for (int c = 0; c < 8; ++c) {
        int j = lane + 64 * c;
        float w = W_h2h[h * H_N + j];
        Whp[c] = w > 0.0f ? w : 0.0f;
        wh[c]  = 0.0f;
        float m = (j < 409) ? 1.0f : -1.0f;   // sign_h (no exist in MASK_H2H)
        msk[c] = (j == h) ? 0.0f : m;         // zero diagonal
    }
    const float bh  = b_h2h[h];
    const float k0 = kappa[0], k1 = kappa[1], k2 = kappa[2];
    const float k3 = kappa[3], k4 = kappa[4], k5 = kappa[5];
    const float ba0 = b_attn[0], ba1 = b_attn[1], ba2 = b_attn[2], ba3 = b_attn[3];

    float state = 0.0f;
    unsigned* cnt = barrier_cnt + b * 32;   // 128B stride between batch groups

    __syncthreads();   // s_ea ready

    for (int t = 0; t < T_N; ++t) {
        // ---- previous output row (zeros at t=0) ----
        float outp[8];
        if (t == 0) {
#pragma unroll
            for (int c = 0; c < 8; ++c) outp[c] = 0.0f;
        } else {
            const float* hrow = hs + ((size_t)(t - 1) * B_N + b) * H_N;
#pragma unroll
            for (int c = 0; c < 8; ++c) outp[c] = hrow[lane + 64 * c];
        }

        // ---- attention: logits[g] = sum_j out[j]*eff_attn[g,j] + b_attn ----
        float l0 = 0.f, l1 = 0.f, l2 = 0.f, l3 = 0.f;
#pragma unroll
        for (int c = 0; c < 8; ++c) {
            int j = lane + 64 * c;
            l0 = fmaf(outp[c], s_ea[0 * H_N + j], l0);
            l1 = fmaf(outp[c], s_ea[1 * H_N + j], l1);
            l2 = fmaf(outp[c], s_ea[2 * H_N + j], l2);
            l3 = fmaf(outp[c], s_ea[3 * H_N + j], l3);
        }
        l0 = wave_sum(l0) + ba0;
        l1 = wave_sum(l1) + ba1;
        l2 = wave_sum(l2) + ba2;
        l3 = wave_sum(l3) + ba3;
        float mx = fmaxf(fmaxf(l0, l1), fmaxf(l2, l3));
        float e0 = expf(l0 - mx), e1 = expf(l1 - mx);
        float e2 = expf(l2 - mx), e3 = expf(l3 - mx);
        float inv = 4.0f / (e0 + e1 + e2 + e3);   // fold *G into softmax
        float awv[4] = { e0 * inv, e1 * inv, e2 * inv, e3 * inv };

        // ---- xin = relu(x_t) * af * G ; i = lane+64c -> group c exactly ----
        const float* xrow = x + ((size_t)t * B_N + b) * I_N;
        float xin[4];
#pragma unroll
        for (int c = 0; c < 4; ++c) {
            float xv = xrow[lane + 64 * c];
            xv = xv > 0.0f ? xv : 0.0f;
            xin[c] = xv * awv[c];
        }

        // ---- total[b,h] = (Wxp+wx)·xin + ((Whp+wh)*mask)·out + b_h2h ----
        float acc = 0.0f;
#pragma unroll
        for (int c = 0; c < 4; ++c) acc = fmaf(Wxp[c] + wx[c], xin[c], acc);
#pragma unroll
        for (int c = 0; c < 8; ++c) acc = fmaf((Whp[c] + wh[c]) * msk[c], outp[c], acc);
        float total = wave_sum(acc) + bh;

        state = state * (1.0f - AX_) + total * AX_;
        float ns = state > 0.0f ? state : 0.0f;
        float no = tanhf(ns);

        // ---- plasticity update (clamped at -relu(W)) ----
        float R  = Rs[t * B_N + b];
        float dr = DT_ * R;
#pragma unroll
        for (int c = 0; c < 4; ++c) {
            float hebb = fmaf(k2 * no, xin[c], fmaf(k0, xin[c], k1 * no));
            float u = fmaf(wx[c], (1.0f - AW_), dr * hebb);
            wx[c] = fmaxf(u, -Wxp[c]);
        }
#pragma unroll
        for (int c = 0; c < 8; ++c) {
            float hebb = fmaf(k5 * no, outp[c], fmaf(k3, outp[c], k4 * no));
            float u = fmaf(wh[c], (1.0f - AW_), dr * hebb);
            wh[c] = fmaxf(u, -Whp[c]);
        }

        // ---- publish new_out directly into hs output ----
        if (lane == 0) hs[((size_t)t * B_N + b) * H_N + h] = no;

        // ---- 32-block per-batch barrier (monotonic counter) ----
        __syncthreads();                  // drains each wave's stores (vmcnt 0)
        if (tid == 0) {
            __threadfence();              // agent-scope release (L2 writeback)
            __hip_atomic_fetch_add(cnt, 1u, __ATOMIC_RELEASE, __HIP_MEMORY_SCOPE_AGENT);
            unsigned target = 32u * (unsigned)(t + 1);
            while (__hip_atomic_load(cnt, __ATOMIC_ACQUIRE, __HIP_MEMORY_SCOPE_AGENT) < target) { }
            __threadfence();              // agent-scope acquire (cache inv)
        }
        __syncthreads();
    }

    // ---- epilogue: os[t,b,o] = sum_h hs[t,b,h] * relu(W_h2o[o,h]) * exist[h]
    // per-batch group has 512 waves covering (t,o) in [64]x[8]; needs only own b.
    {
        int v = ((bk & 31) << 4) | wid;   // 0..511
        int t = v >> 3;
        int o = v & 7;
        const float* hrow = hs + ((size_t)t * B_N + b) * H_N;
        float acc = 0.0f;
#pragma unroll
        for (int c = 0; c < 8; ++c) {
            int j = lane + 64 * c;
            float w = W_h2o[o * H_N + j];
            w = w > 0.0f ? w : 0.0f;
            if (j >= 410) w = 0.0f;       // MASK_H2O = exist only
            acc = fmaf(hrow[j], w, acc);
        }
        acc = wave_sum(acc);
        if (lane == 0) os[t * (B_N * O_N) + b * O_N + o] = acc;
    }
}

extern "C" void kernel_launch(void* const* d_in, const int* in_sizes, int n_in,
                              void* d_out, int out_size, void* d_ws, size_t ws_size,
                              hipStream_t stream) {
    (void)in_sizes; (void)n_in; (void)out_size; (void)ws_size;
    const float* x      = (const float*)d_in[0];
    const float* Rs     = (const float*)d_in[1];
    const float* W_x2h  = (const float*)d_in[2];
    const float* W_h2h  = (const float*)d_in[3];
    const float* b_h2h  = (const float*)d_in[4];
    const float* W_h2o  = (const float*)d_in[5];
    const float* W_attn = (const float*)d_in[6];
    const float* b_attn = (const float*)d_in[7];
    const float* kappa  = (const float*)d_in[8];
    float* out = (float*)d_out;
    unsigned* cnt = (unsigned*)d_ws;

    // zero the barrier counters every call (graph-capture-legal memset node)
    hipMemsetAsync(d_ws, 0, B_N * 32 * sizeof(unsigned), stream);
    rnn_scan<<<dim3(256), dim3(1024), 0, stream>>>(
        x, Rs, W_x2h, W_h2h, b_h2h, W_h2o, W_attn, b_attn, kappa, out, cnt);
}

// Round 2
// 264.134 us; speedup vs baseline: 3.6779x; 3.6779x over previous
//
#include <hip/hip_runtime.h>

// SimpleRNN: T=64 steps, B=8, H=512, I=256, O=8, G=4, GS=64
// E_H=409 (sign +1 for j<=408, -1 for j>=409); ZC=102 (exist: j<410)
#define T_N 64
#define B_N 8
#define H_N 512
#define I_N 256
#define O_N 8
#define G_N 4

constexpr float DT_ = 0.02f;
constexpr float AX_ = 0.2f;   // DT/0.1
constexpr float AW_ = 0.02f;  // DT/1.0

// Coherent (LLC-level) accesses: RELAXED+AGENT emits sc0/sc1 ops that bypass
// the non-coherent per-CU L1 and per-XCD L2 -> no fences (buffer_wbl2 /
// buffer_inv) are ever needed for cross-block visibility.
__device__ __forceinline__ float ldf_agent(const float* p) {
    return __hip_atomic_load(p, __ATOMIC_RELAXED, __HIP_MEMORY_SCOPE_AGENT);
}
__device__ __forceinline__ void stf_agent(float* p, float v) {
    __hip_atomic_store(p, v, __ATOMIC_RELAXED, __HIP_MEMORY_SCOPE_AGENT);
}
__device__ __forceinline__ unsigned ldu_agent(const unsigned* p) {
    return __hip_atomic_load(p, __ATOMIC_RELAXED, __HIP_MEMORY_SCOPE_AGENT);
}

// One wave per (b,h). 256 blocks x 1024 threads = 4096 waves.
// b = bk & 7  -> all 32 blocks of a batch land on one XCD (round-robin dispatch).
// Plastic state wx[b,h,:], wh[b,h,:] lives in registers for all 64 steps.
__global__ __launch_bounds__(1024) void rnn_scan(
    const float* __restrict__ x, const float* __restrict__ Rs,
    const float* __restrict__ W_x2h, const float* __restrict__ W_h2h,
    const float* __restrict__ b_h2h, const float* __restrict__ W_h2o,
    const float* __restrict__ W_attn, const float* __restrict__ b_attn,
    const float* __restrict__ kappa, float* __restrict__ d_out,
    unsigned* __restrict__ barrier_cnt)
{
    float* os = d_out;                      // [T][B][O]
    float* hs = d_out + T_N * B_N * O_N;    // [T][B][H]

    const int tid  = threadIdx.x;
    const int wid  = tid >> 6;
    const int lane = tid & 63;
    const int bk   = blockIdx.x;            // 0..255
    const int b    = bk & 7;                // XCD-pinned batch
    const int hg   = bk >> 3;               // 0..31
    const int h    = (hg << 4) | wid;       // 0..511

    // ---- loop-invariant per-lane constants (all in registers) ----
    // eff_attn[g][j] = relu(W_attn)*sign*exist, j = lane + 64c
    float ea[G_N][8];
#pragma unroll
    for (int g = 0; g < G_N; ++g)
#pragma unroll
        for (int c = 0; c < 8; ++c) {
            int j = lane + 64 * c;
            float w = fmaxf(W_attn[g * H_N + j], 0.0f);
            float m = (j < 409) ? 1.0f : ((j < 410) ? -1.0f : 0.0f);
            ea[g][c] = w * m;
        }

    float Wxp[4], wx[4];
#pragma unroll
    for (int c = 0; c < 4; ++c) {
        Wxp[c] = fmaxf(W_x2h[h * I_N + lane + 64 * c], 0.0f);
        wx[c]  = 0.0f;
    }
    float Whp[8], wh[8], msk[8];
#pragma unroll
    for (int c = 0; c < 8; ++c) {
        int j = lane + 64 * c;
        Whp[c] = fmaxf(W_h2h[h * H_N + j], 0.0f);
        wh[c]  = 0.0f;
        float m = (j <= 408) ? 1.0f : -1.0f;   // sign only (MASK_H2H has no exist)
        msk[c] = (j == h) ? 0.0f : m;          // zero diagonal
    }
    const float bh = b_h2h[h];
    const float k0 = kappa[0], k1 = kappa[1], k2 = kappa[2];
    const float k3 = kappa[3], k4 = kappa[4], k5 = kappa[5];
    const float ba0 = b_attn[0], ba1 = b_attn[1], ba2 = b_attn[2], ba3 = b_attn[3];

    float state = 0.0f;
    unsigned* cnt = barrier_cnt + b * 32;    // 128B stride between batches

    // prefetch t=0 inputs
    float xv[4];
#pragma unroll
    for (int c = 0; c < 4; ++c) xv[c] = fmaxf(x[(size_t)b * I_N + lane + 64 * c], 0.0f);
    float Rcur = Rs[b];

    for (int t = 0; t < T_N; ++t) {
        // ---- previous output row (zeros at t=0), coherent loads ----
        float outp[8];
        if (t == 0) {
#pragma unroll
            for (int c = 0; c < 8; ++c) outp[c] = 0.0f;
        } else {
            const float* hrow = hs + ((size_t)(t - 1) * B_N + b) * H_N;
#pragma unroll
            for (int c = 0; c < 8; ++c) outp[c] = ldf_agent(hrow + lane + 64 * c);
        }

        // ---- 9 fused wave reductions: 4 attn logits, 4 x-dot group
        //      partials, 1 h2h dot (all independent -> one shuffle tree) ----
        float red[9];
#pragma unroll
        for (int g = 0; g < G_N; ++g) {
            float l = 0.0f;
#pragma unroll
            for (int c = 0; c < 8; ++c) l = fmaf(outp[c], ea[g][c], l);
            red[g] = l;
        }
#pragma unroll
        for (int c = 0; c < 4; ++c)     // group c == input chunk c (GS=64)
            red[4 + c] = (Wxp[c] + wx[c]) * xv[c];
        {
            float a = 0.0f;
#pragma unroll
            for (int c = 0; c < 8; ++c) a = fmaf((Whp[c] + wh[c]) * msk[c], outp[c], a);
            red[8] = a;
        }
#pragma unroll
        for (int off = 32; off >= 1; off >>= 1) {
#pragma unroll
            for (int k = 0; k < 9; ++k) red[k] += __shfl_xor(red[k], off, 64);
        }

        // ---- softmax over 4 logits (fold *G into the normalizer) ----
        float l0 = red[0] + ba0, l1 = red[1] + ba1;
        float l2 = red[2] + ba2, l3 = red[3] + ba3;
        float mx = fmaxf(fmaxf(l0, l1), fmaxf(l2, l3));
        float e0 = expf(l0 - mx), e1 = expf(l1 - mx);
        float e2 = expf(l2 - mx), e3 = expf(l3 - mx);
        float inv = 4.0f / (e0 + e1 + e2 + e3);
        float aw0 = e0 * inv, aw1 = e1 * inv, aw2 = e2 * inv, aw3 = e3 * inv;

        float total = red[4] * aw0 + red[5] * aw1 + red[6] * aw2 + red[7] * aw3
                    + red[8] + bh;

        state = state * (1.0f - AX_) + total * AX_;
        float ns = fmaxf(state, 0.0f);
        float no = tanhf(ns);

        // ---- publish new_out (coherent store), arrive at barrier ----
        if (lane == 0) stf_agent(&hs[((size_t)t * B_N + b) * H_N + h], no);
        __syncthreads();                 // implies vmcnt(0): store ack'd at LLC
        if (tid == 0)
            __hip_atomic_fetch_add(cnt, 1u, __ATOMIC_RELAXED, __HIP_MEMORY_SCOPE_AGENT);

        // ---- plasticity update + next-step prefetch (overlaps the poll) ----
        float xin[4];
#pragma unroll
        for (int c = 0; c < 4; ++c) xin[c] = xv[c] * ((c == 0) ? aw0 : (c == 1) ? aw1 : (c == 2) ? aw2 : aw3);
        float dr = DT_ * Rcur;
#pragma unroll
        for (int c = 0; c < 4; ++c) {
            float hebb = fmaf(k2 * no, xin[c], fmaf(k0, xin[c], k1 * no));
            wx[c] = fmaxf(fmaf(wx[c], 1.0f - AW_, dr * hebb), -Wxp[c]);
        }
#pragma unroll
        for (int c = 0; c < 8; ++c) {
            float hebb = fmaf(k5 * no, outp[c], fmaf(k3, outp[c], k4 * no));
            wh[c] = fmaxf(fmaf(wh[c], 1.0f - AW_, dr * hebb), -Whp[c]);
        }

        float xvn[4] = {0.f, 0.f, 0.f, 0.f};
        float Rn = 0.0f;
        if (t + 1 < T_N) {
            const float* xr = x + ((size_t)(t + 1) * B_N + b) * I_N;
#pragma unroll
            for (int c = 0; c < 4; ++c) xvn[c] = xr[lane + 64 * c];
            Rn = Rs[(t + 1) * B_N + b];
        }

        // ---- leader polls (relaxed, coherent): no cache invalidates ----
        if (tid == 0) {
            unsigned target = 32u * (unsigned)(t + 1);
            while (ldu_agent(cnt) < target) __builtin_amdgcn_s_sleep(1);
        }
        __syncthreads();

#pragma unroll
        for (int c = 0; c < 4; ++c) xv[c] = fmaxf(xvn[c], 0.0f);
        Rcur = Rn;
    }

    // ---- epilogue: os[t,b,o] = sum_h hs[t,b,h] * relu(W_h2o[o,h]) * exist ----
    {
        int v = (hg << 4) | wid;   // 0..511
        int t = v >> 3;
        int o = v & 7;
        const float* hrow = hs + ((size_t)t * B_N + b) * H_N;
        float acc = 0.0f;
#pragma unroll
        for (int c = 0; c < 8; ++c) {
            int j = lane + 64 * c;
            float w = fmaxf(W_h2o[o * H_N + j], 0.0f);
            if (j >= 410) w = 0.0f;            // MASK_H2O = exist only
            acc = fmaf(ldf_agent(hrow + j), w, acc);
        }
#pragma unroll
        for (int off = 32; off >= 1; off >>= 1) acc += __shfl_xor(acc, off, 64);
        if (lane == 0) os[t * (B_N * O_N) + b * O_N + o] = acc;
    }
}

extern "C" void kernel_launch(void* const* d_in, const int* in_sizes, int n_in,
                              void* d_out, int out_size, void* d_ws, size_t ws_size,
                              hipStream_t stream) {
    (void)in_sizes; (void)n_in; (void)out_size; (void)ws_size;
    const float* x      = (const float*)d_in[0];
    const float* Rs     = (const float*)d_in[1];
    const float* W_x2h  = (const float*)d_in[2];
    const float* W_h2h  = (const float*)d_in[3];
    const float* b_h2h  = (const float*)d_in[4];
    const float* W_h2o  = (const float*)d_in[5];
    const float* W_attn = (const float*)d_in[6];
    const float* b_attn = (const float*)d_in[7];
    const float* kappa  = (const float*)d_in[8];
    float* out = (float*)d_out;
    unsigned* cnt = (unsigned*)d_ws;

    // zero the barrier counters every call (graph-capture-legal memset node)
    hipMemsetAsync(d_ws, 0, B_N * 32 * sizeof(unsigned), stream);
    rnn_scan<<<dim3(256), dim3(1024), 0, stream>>>(
        x, Rs, W_x2h, W_h2h, b_h2h, W_h2o, W_attn, b_attn, kappa, out, cnt);
}